// Round 7
// baseline (222.153 us; speedup 1.0000x reference)
//
#include <hip/hip_runtime.h>

// B=8, C=12, Ny=Nx=512, 3x3 depthwise conv SAME pad=1, channel-reduced, + Rq + Dq.
// Round-6 software pipeline + VGPR cap 128 via __launch_bounds__(256, 2).
// Empirical toolchain rule (r3-r6): VGPR cap = 256 / min_waves_arg
//   (256,8)->32 (r4, spilled), (256,4)->64 (r3/r5, spilled), none->200 (r6, occ 11%).
// 128 = fits pipeline's ~103 live regs AND keeps 4 waves/SIMD (m69 boundary).
#define NY 512
#define NX 512
#define CC 12

__device__ __forceinline__ void row_conv(const float4& v0, const float4& v1,
                                         float w0, float w1, float w2, int lane,
                                         float4& a0, float4& a1)
{
    float l0 = __shfl_up(v1.w, 1);    // px 8i-1 from lane i-1
    if (lane == 0) l0 = 0.f;          // image left edge
    float r1 = __shfl_down(v0.x, 1);  // px 8i+8 from lane i+1
    if (lane == 63) r1 = 0.f;         // image right edge

    a0.x += w0*l0   + w1*v0.x + w2*v0.y;
    a0.y += w0*v0.x + w1*v0.y + w2*v0.z;
    a0.z += w0*v0.y + w1*v0.z + w2*v0.w;
    a0.w += w0*v0.z + w1*v0.w + w2*v1.x;
    a1.x += w0*v0.w + w1*v1.x + w2*v1.y;
    a1.y += w0*v1.x + w1*v1.y + w2*v1.z;
    a1.z += w0*v1.y + w1*v1.z + w2*v1.w;
    a1.w += w0*v1.z + w1*v1.w + w2*r1;
}

// 6 vector loads of one plane's 3 rows into named regs (assignment, not decl)
#define LOAD6(P, base)                              \
    P##t0 = *(const float4*)((base) + off_t);       \
    P##t1 = *(const float4*)((base) + off_t + 4);   \
    P##m0 = *(const float4*)((base) + off_m);       \
    P##m1 = *(const float4*)((base) + off_m + 4);   \
    P##b0 = *(const float4*)((base) + off_b);       \
    P##b1 = *(const float4*)((base) + off_b + 4);

#define CONV6(P, A0, A1)                                     \
    row_conv(P##t0, P##t1, w00, w01, w02, lane, A0, A1);     \
    row_conv(P##m0, P##m1, w10, w11, w12, lane, A0, A1);     \
    row_conv(P##b0, P##b1, w20, w21, w22, lane, A0, A1);

// One channel: issue im(c) + re(c+1) loads, then convolve re(c) (already
// resident, no wait) and im(c) (waits only its own 6 loads).
#define CHANNEL_STEP(C, CUR, NXT)                                         \
    {                                                                     \
        const float* pim_ = ci_base + (size_t)(C) * PS;                   \
        LOAD6(i, pim_)                                                    \
        if ((C) + 1 < CC) {                                               \
            const float* pre_ = cr_base + (size_t)((C) + 1) * PS;         \
            LOAD6(NXT, pre_)                                              \
        }                                                                 \
        const float* f_ = filt + (C) * 9;                                 \
        const float w00 = f_[0] * m_top, w01 = f_[1] * m_top,             \
                    w02 = f_[2] * m_top;                                  \
        const float w10 = f_[3], w11 = f_[4], w12 = f_[5];                \
        const float w20 = f_[6] * m_bot, w21 = f_[7] * m_bot,             \
                    w22 = f_[8] * m_bot;                                  \
        CONV6(CUR, ar0, ar1)                                              \
        CONV6(i, ai0, ai1)                                                \
    }

// Block: 256 threads = 4 waves, each owning one full row (re+im).
// Grid (NY/4, B) = (128, 8) = 1024 blocks -> 4096 waves, 16 waves/CU.
__global__ __launch_bounds__(256, 2)
void momentum_kernel(const float* __restrict__ Rq_re, const float* __restrict__ Rq_im,
                     const float* __restrict__ Dq_re, const float* __restrict__ Dq_im,
                     const float* __restrict__ cache_re, const float* __restrict__ cache_im,
                     const float* __restrict__ filt, float* __restrict__ out)
{
    const int tid  = threadIdx.x;
    const int wave = tid >> 6;
    const int lane = tid & 63;
    const int y    = blockIdx.x * 4 + wave;
    const int b    = blockIdx.y;
    const int x0   = lane * 8;

    // y-halo: clamped row + 0/1 weight mask (wave-uniform, branch-free loads)
    const int   ym1   = (y > 0)      ? y - 1 : 0;
    const int   yp1   = (y < NY - 1) ? y + 1 : NY - 1;
    const float m_top = (y > 0)      ? 1.f : 0.f;
    const float m_bot = (y < NY - 1) ? 1.f : 0.f;

    const int off_t = ym1 * NX + x0;
    const int off_m = y   * NX + x0;
    const int off_b = yp1 * NX + x0;

    const size_t PS = (size_t)NY * NX;
    const float* cr_base = cache_re + (size_t)b * CC * PS;
    const float* ci_base = cache_im + (size_t)b * CC * PS;

    // ---- pointwise: Rq + Dq (8 independent loads, one batch) ----
    float4 ar0, ar1, ai0, ai1;
    {
        const int base = (b * NY + y) * NX + x0;
        const float4 q0 = *(const float4*)(Rq_re + base);
        const float4 q1 = *(const float4*)(Rq_re + base + 4);
        const float4 d0 = *(const float4*)(Dq_re + base);
        const float4 d1 = *(const float4*)(Dq_re + base + 4);
        const float4 u0 = *(const float4*)(Rq_im + base);
        const float4 u1 = *(const float4*)(Rq_im + base + 4);
        const float4 e0 = *(const float4*)(Dq_im + base);
        const float4 e1 = *(const float4*)(Dq_im + base + 4);
        ar0 = make_float4(q0.x + d0.x, q0.y + d0.y, q0.z + d0.z, q0.w + d0.w);
        ar1 = make_float4(q1.x + d1.x, q1.y + d1.y, q1.z + d1.z, q1.w + d1.w);
        ai0 = make_float4(u0.x + e0.x, u0.y + e0.y, u0.z + e0.z, u0.w + e0.w);
        ai1 = make_float4(u1.x + e1.x, u1.y + e1.y, u1.z + e1.z, u1.w + e1.w);
    }

    // ---- pipelined channel loop: r*/n* ping-pong re-buffers, i* im-buffer ----
    float4 rt0, rt1, rm0, rm1, rb0, rb1;   // re buffer A
    float4 nt0, nt1, nm0, nm1, nb0, nb1;   // re buffer B
    float4 it0, it1, im0, im1, ib0, ib1;   // im buffer

    LOAD6(r, cr_base)                       // prologue: re(0)

    #pragma unroll
    for (int cc = 0; cc < CC; cc += 2) {
        CHANNEL_STEP(cc,     r, n)
        CHANNEL_STEP(cc + 1, n, r)
    }

    // ---- store (B, 2, NY, NX) ----
    float* o_re = out + ((size_t)(b * 2 + 0) * NY + y) * NX + x0;
    float* o_im = out + ((size_t)(b * 2 + 1) * NY + y) * NX + x0;
    *(float4*)(o_re)     = ar0;
    *(float4*)(o_re + 4) = ar1;
    *(float4*)(o_im)     = ai0;
    *(float4*)(o_im + 4) = ai1;
}

extern "C" void kernel_launch(void* const* d_in, const int* in_sizes, int n_in,
                              void* d_out, int out_size, void* d_ws, size_t ws_size,
                              hipStream_t stream) {
    const float* Rq_re    = (const float*)d_in[0];
    const float* Rq_im    = (const float*)d_in[1];
    const float* Dq_re    = (const float*)d_in[2];
    const float* Dq_im    = (const float*)d_in[3];
    const float* cache_re = (const float*)d_in[4];
    const float* cache_im = (const float*)d_in[5];
    const float* filt     = (const float*)d_in[6];
    float* out = (float*)d_out;

    const int B = in_sizes[0] / (NY * NX);   // = 8

    dim3 block(256);
    dim3 grid(NY / 4, B);
    momentum_kernel<<<grid, block, 0, stream>>>(Rq_re, Rq_im, Dq_re, Dq_im,
                                                cache_re, cache_im, filt, out);
}

// Round 8
// 75.697 us; speedup vs baseline: 2.9348x; 2.9348x over previous
//
#include <hip/hip_runtime.h>
#include <stdint.h>

// B=8, C=12, Ny=Nx=512, 3x3 depthwise conv SAME pad=1, channel-reduced, + Rq + Dq.
// LDS pipeline version: global_load_lds (no VGPR round-trip) + double-buffered
// channel chunks + counted vmcnt waits (m97/m218 pattern). Register pipelining
// (r5-r7) always spilled; this moves latency-hiding into LDS + waitcnt.
#define NY 512
#define NX 512
#define CC 12

#define PS      (NY * NX)
#define PLANE_F 3072                 // 6 rows * 512 floats per plane chunk
#define BUF_F   (2 * PLANE_F)        // re + im chunk
#define FILT_OFF (2 * BUF_F)         // float index of filter block in LDS
#define LDS_F   (2 * BUF_F + 108)    // 12396 floats = 49584 B -> 3 blocks/CU

#define GLDS16(gsrc, ldst)                                                   \
    __builtin_amdgcn_global_load_lds(                                       \
        (const __attribute__((address_space(1))) void*)(gsrc),              \
        (__attribute__((address_space(3))) void*)(ldst), 16, 0, 0)

#define WAITV6() asm volatile("s_waitcnt vmcnt(6)" ::: "memory")
#define WAITV0() asm volatile("s_waitcnt vmcnt(0)" ::: "memory")
#define WAITLG() asm volatile("s_waitcnt lgkmcnt(0)" ::: "memory")
#define BAR()    __builtin_amdgcn_s_barrier()

// One input row (512 px) held as two 16B-stride segments: seg0 = px[4*lane..],
// seg1 = px[256+4*lane..]. ds_read_b128 at 16B/lane stride = conflict-free.
__device__ __forceinline__ void conv_row(const float* Lrow, int lane,
                                         float w0, float w1, float w2,
                                         float4& A0, float4& A1)
{
    const float4 v0 = *(const float4*)(Lrow + lane * 4);
    const float4 v1 = *(const float4*)(Lrow + 256 + lane * 4);

    float l0 = __shfl_up(v0.w, 1);            // px 4i-1
    if (lane == 0) l0 = 0.f;                  // image left edge
    float r0 = __shfl_down(v0.x, 1);          // px 4i+4
    const float c0 = __shfl(v1.x, 0);         // px 256 (for lane 63)
    if (lane == 63) r0 = c0;
    float l1 = __shfl_up(v1.w, 1);            // px 255+4i
    const float c1 = __shfl(v0.w, 63);        // px 255 (for lane 0)
    if (lane == 0) l1 = c1;
    float r1 = __shfl_down(v1.x, 1);          // px 260+4i
    if (lane == 63) r1 = 0.f;                 // image right edge

    A0.x += w0*l0   + w1*v0.x + w2*v0.y;
    A0.y += w0*v0.x + w1*v0.y + w2*v0.z;
    A0.z += w0*v0.y + w1*v0.z + w2*v0.w;
    A0.w += w0*v0.z + w1*v0.w + w2*r0;
    A1.x += w0*l1   + w1*v1.x + w2*v1.y;
    A1.y += w0*v1.x + w1*v1.y + w2*v1.z;
    A1.z += w0*v1.y + w1*v1.z + w2*v1.w;
    A1.w += w0*v1.z + w1*v1.w + w2*r1;
}

// Stage channel c's (re, im) 6-row chunks into buf (c&1): 6 DMA issues/thread.
#define STAGE(c) do {                                                        \
    const float* gr_ = cr_base + (size_t)(c) * PS;                           \
    const float* gi_ = ci_base + (size_t)(c) * PS;                           \
    float* lb_ = lds + (((c) & 1) ? BUF_F : 0);                              \
    GLDS16(gr_ + g_off0, lb_ + l_off0);                                      \
    GLDS16(gr_ + g_off1, lb_ + l_off1);                                      \
    GLDS16(gr_ + g_off2, lb_ + l_off2);                                      \
    GLDS16(gi_ + g_off0, lb_ + PLANE_F + l_off0);                            \
    GLDS16(gi_ + g_off1, lb_ + PLANE_F + l_off1);                            \
    GLDS16(gi_ + g_off2, lb_ + PLANE_F + l_off2);                            \
} while (0)

#define COMPUTE(c) do {                                                      \
    const float* f_ = lds + FILT_OFF + (c) * 9;                              \
    const float w00 = f_[0]*m_top, w01 = f_[1]*m_top, w02 = f_[2]*m_top;     \
    const float w10 = f_[3],       w11 = f_[4],       w12 = f_[5];           \
    const float w20 = f_[6]*m_bot, w21 = f_[7]*m_bot, w22 = f_[8]*m_bot;     \
    const float* Lr = lds + (((c) & 1) ? BUF_F : 0);                         \
    const float* Li = Lr + PLANE_F;                                          \
    conv_row(Lr + st * NX, lane, w00, w01, w02, ar0, ar1);                   \
    conv_row(Lr + sm * NX, lane, w10, w11, w12, ar0, ar1);                   \
    conv_row(Lr + sb * NX, lane, w20, w21, w22, ar0, ar1);                   \
    conv_row(Li + st * NX, lane, w00, w01, w02, ai0, ai1);                   \
    conv_row(Li + sm * NX, lane, w10, w11, w12, ai0, ai1);                   \
    conv_row(Li + sb * NX, lane, w20, w21, w22, ai0, ai1);                   \
} while (0)

// Iter c: wait chunk c (leave c+1 in flight), sync, compute, sync, stage c+2.
#define CH(c) do {                                                           \
    if ((c) == CC - 1) { WAITV0(); } else { WAITV6(); }                      \
    BAR();                                                                   \
    COMPUTE(c);                                                              \
    WAITLG();                                                                \
    BAR();                                                                   \
    if ((c) + 2 < CC) STAGE((c) + 2);                                        \
} while (0)

// Block: 256 threads = 4 waves = 4 output rows (re+im). Grid 1024 blocks.
__global__ __launch_bounds__(256)
void momentum_kernel(const float* __restrict__ Rq_re, const float* __restrict__ Rq_im,
                     const float* __restrict__ Dq_re, const float* __restrict__ Dq_im,
                     const float* __restrict__ cache_re, const float* __restrict__ cache_im,
                     const float* __restrict__ filt, float* __restrict__ out)
{
    __shared__ __align__(16) float lds[LDS_F];

    const int tid  = threadIdx.x;
    const int wave = tid >> 6;
    const int lane = tid & 63;

    // XCD-aware swizzle: bid%8 = XCD -> give XCD k the whole batch k
    // (halo rows then reuse within one XCD's L2). 1024 % 8 == 0 -> bijective.
    const int bid = blockIdx.x + (int)(blockIdx.y * gridDim.x);
    const int swz = (bid & 7) * 128 + (bid >> 3);
    const int b   = swz >> 7;
    const int y0  = (swz & 127) * 4;
    const int y   = y0 + wave;

    // 6-row staged window: always 6 valid contiguous rows (clamped at edges);
    // out-of-image taps handled by weight masks (exact zeros, no NaN risk).
    const int chunk0 = (y0 == 0) ? 0 : ((y0 == NY - 4) ? NY - 6 : y0 - 1);
    const int st = ((y > 0) ? y - 1 : 0) - chunk0;
    const int sm = y - chunk0;
    const int sb = ((y < NY - 1) ? y + 1 : NY - 1) - chunk0;
    const float m_top = (y > 0)      ? 1.f : 0.f;
    const float m_bot = (y < NY - 1) ? 1.f : 0.f;

    // stage offsets (floats): per round 256 thr x 16 B = 1024 floats
    const int wv    = wave * 256;
    const int g_off0 = chunk0 * NX + wv + lane * 4;
    const int g_off1 = g_off0 + 1024;
    const int g_off2 = g_off0 + 2048;
    const int l_off0 = wv;
    const int l_off1 = l_off0 + 1024;
    const int l_off2 = l_off0 + 2048;

    const float* cr_base = cache_re + (size_t)b * CC * PS;
    const float* ci_base = cache_im + (size_t)b * CC * PS;

    // ---- pointwise Rq + Dq (consume immediately: keeps vmcnt queue clean) ----
    float4 ar0, ar1, ai0, ai1;
    {
        const int base = (b * NY + y) * NX;
        const int o0 = base + lane * 4, o1 = base + 256 + lane * 4;
        const float4 q0 = *(const float4*)(Rq_re + o0);
        const float4 q1 = *(const float4*)(Rq_re + o1);
        const float4 d0 = *(const float4*)(Dq_re + o0);
        const float4 d1 = *(const float4*)(Dq_re + o1);
        const float4 u0 = *(const float4*)(Rq_im + o0);
        const float4 u1 = *(const float4*)(Rq_im + o1);
        const float4 e0 = *(const float4*)(Dq_im + o0);
        const float4 e1 = *(const float4*)(Dq_im + o1);
        ar0 = make_float4(q0.x+d0.x, q0.y+d0.y, q0.z+d0.z, q0.w+d0.w);
        ar1 = make_float4(q1.x+d1.x, q1.y+d1.y, q1.z+d1.z, q1.w+d1.w);
        ai0 = make_float4(u0.x+e0.x, u0.y+e0.y, u0.z+e0.z, u0.w+e0.w);
        ai1 = make_float4(u1.x+e1.x, u1.y+e1.y, u1.z+e1.z, u1.w+e1.w);
    }

    // ---- filter -> LDS (before staging so its vmem wait can't drain stages) ----
    if (tid < 108) lds[FILT_OFF + tid] = filt[tid];

    // ---- prologue: 2 chunks in flight ----
    STAGE(0);
    STAGE(1);
    WAITLG();            // filter ds_writes serviced before CH(0)'s barrier

    CH(0);  CH(1);  CH(2);  CH(3);  CH(4);  CH(5);
    CH(6);  CH(7);  CH(8);  CH(9);  CH(10); CH(11);

    // ---- store (B, 2, NY, NX), two segments per plane ----
    float* o_re = out + ((size_t)(b * 2 + 0) * NY + y) * NX;
    float* o_im = out + ((size_t)(b * 2 + 1) * NY + y) * NX;
    *(float4*)(o_re + lane * 4)       = ar0;
    *(float4*)(o_re + 256 + lane * 4) = ar1;
    *(float4*)(o_im + lane * 4)       = ai0;
    *(float4*)(o_im + 256 + lane * 4) = ai1;
}

extern "C" void kernel_launch(void* const* d_in, const int* in_sizes, int n_in,
                              void* d_out, int out_size, void* d_ws, size_t ws_size,
                              hipStream_t stream) {
    const float* Rq_re    = (const float*)d_in[0];
    const float* Rq_im    = (const float*)d_in[1];
    const float* Dq_re    = (const float*)d_in[2];
    const float* Dq_im    = (const float*)d_in[3];
    const float* cache_re = (const float*)d_in[4];
    const float* cache_im = (const float*)d_in[5];
    const float* filt     = (const float*)d_in[6];
    float* out = (float*)d_out;

    dim3 block(256);
    dim3 grid(NY / 4, 8);   // 1024 blocks; swizzle in-kernel maps XCD->batch
    momentum_kernel<<<grid, block, 0, stream>>>(Rq_re, Rq_im, Dq_re, Dq_im,
                                                cache_re, cache_im, filt, out);
}

// Round 9
// 52.602 us; speedup vs baseline: 4.2233x; 1.4391x over previous
//
#include <hip/hip_runtime.h>

// B=8, C=12, Ny=Nx=512, 3x3 depthwise conv SAME pad=1, channel-reduced, + Rq + Dq.
// Round-3 structure (1 wave = 1 full output row, re+im fused, rolled channel
// loop) with TWO changes:
//   1. __launch_bounds__(256) -- NO min-waves arg. r3's (256,4) capped VGPR at
//      64, forcing the compiler to sub-batch each channel's 12 loads (MLP~4).
//      Natural allocation (~96-112) keeps all 12 in flight; 4-5 waves/SIMD
//      still fit, grid (16 waves/CU) stays the occupancy limit.
//   2. Bijective XCD swizzle: XCD k owns batch k's contiguous y-range, so the
//      2x halo re-reads hit local-XCD L2 instead of crossing dies (T1).
#define NY 512
#define NX 512
#define CC 12

__device__ __forceinline__ void row_conv(const float4& v0, const float4& v1,
                                         float w0, float w1, float w2, int lane,
                                         float4& a0, float4& a1)
{
    float l0 = __shfl_up(v1.w, 1);    // px 8i-1 from lane i-1
    if (lane == 0) l0 = 0.f;          // image left edge
    float r1 = __shfl_down(v0.x, 1);  // px 8i+8 from lane i+1
    if (lane == 63) r1 = 0.f;         // image right edge

    a0.x += w0*l0   + w1*v0.x + w2*v0.y;
    a0.y += w0*v0.x + w1*v0.y + w2*v0.z;
    a0.z += w0*v0.y + w1*v0.z + w2*v0.w;
    a0.w += w0*v0.z + w1*v0.w + w2*v1.x;
    a1.x += w0*v0.w + w1*v1.x + w2*v1.y;
    a1.y += w0*v1.x + w1*v1.y + w2*v1.z;
    a1.z += w0*v1.y + w1*v1.z + w2*v1.w;
    a1.w += w0*v1.z + w1*v1.w + w2*r1;
}

// Block: 256 threads = 4 waves, each owning one full row (re+im).
// Grid (NY/4, B) = (128, 8) = 1024 blocks -> 4096 waves, 16 waves/CU.
__global__ __launch_bounds__(256)
void momentum_kernel(const float* __restrict__ Rq_re, const float* __restrict__ Rq_im,
                     const float* __restrict__ Dq_re, const float* __restrict__ Dq_im,
                     const float* __restrict__ cache_re, const float* __restrict__ cache_im,
                     const float* __restrict__ filt, float* __restrict__ out)
{
    const int tid  = threadIdx.x;
    const int wave = tid >> 6;
    const int lane = tid & 63;

    // XCD swizzle: bid%8 = XCD k -> swz in [128k,128(k+1)) -> batch k,
    // contiguous y-groups. 1024 % 8 == 0 -> bijective.
    const int bid = blockIdx.x + (int)(blockIdx.y * gridDim.x);
    const int swz = (bid & 7) * 128 + (bid >> 3);
    const int b   = swz >> 7;
    const int y   = (swz & 127) * 4 + wave;

    const int x0 = lane * 8;

    // y-halo: clamped row + 0/1 weight mask (wave-uniform, branch-free loads)
    const int   ym1   = (y > 0)      ? y - 1 : 0;
    const int   yp1   = (y < NY - 1) ? y + 1 : NY - 1;
    const float m_top = (y > 0)      ? 1.f : 0.f;
    const float m_bot = (y < NY - 1) ? 1.f : 0.f;

    const int off_t = ym1 * NX + x0;
    const int off_m = y   * NX + x0;
    const int off_b = yp1 * NX + x0;

    // ---- pointwise: Rq + Dq (8 independent loads, one batch) ----
    float4 a0, a1, c0, c1;
    {
        const int base = (b * NY + y) * NX + x0;
        const float4 q0 = *(const float4*)(Rq_re + base);
        const float4 q1 = *(const float4*)(Rq_re + base + 4);
        const float4 d0 = *(const float4*)(Dq_re + base);
        const float4 d1 = *(const float4*)(Dq_re + base + 4);
        const float4 u0 = *(const float4*)(Rq_im + base);
        const float4 u1 = *(const float4*)(Rq_im + base + 4);
        const float4 e0 = *(const float4*)(Dq_im + base);
        const float4 e1 = *(const float4*)(Dq_im + base + 4);
        a0 = make_float4(q0.x + d0.x, q0.y + d0.y, q0.z + d0.z, q0.w + d0.w);
        a1 = make_float4(q1.x + d1.x, q1.y + d1.y, q1.z + d1.z, q1.w + d1.w);
        c0 = make_float4(u0.x + e0.x, u0.y + e0.y, u0.z + e0.z, u0.w + e0.w);
        c1 = make_float4(u1.x + e1.x, u1.y + e1.y, u1.z + e1.z, u1.w + e1.w);
    }
    float4 ar0 = a0, ar1 = a1, ai0 = c0, ai1 = c1;

    // ---- channel-reduced depthwise 3x3: 12 unconditional loads per channel ----
    const size_t PS = (size_t)NY * NX;
    const float* cr_base = cache_re + (size_t)b * CC * PS;
    const float* ci_base = cache_im + (size_t)b * CC * PS;

    for (int c = 0; c < CC; ++c) {
        const float* cr = cr_base + (size_t)c * PS;
        const float* ci = ci_base + (size_t)c * PS;

        const float4 rt0 = *(const float4*)(cr + off_t);
        const float4 rt1 = *(const float4*)(cr + off_t + 4);
        const float4 rm0 = *(const float4*)(cr + off_m);
        const float4 rm1 = *(const float4*)(cr + off_m + 4);
        const float4 rb0 = *(const float4*)(cr + off_b);
        const float4 rb1 = *(const float4*)(cr + off_b + 4);
        const float4 it0 = *(const float4*)(ci + off_t);
        const float4 it1 = *(const float4*)(ci + off_t + 4);
        const float4 im0 = *(const float4*)(ci + off_m);
        const float4 im1 = *(const float4*)(ci + off_m + 4);
        const float4 ib0 = *(const float4*)(ci + off_b);
        const float4 ib1 = *(const float4*)(ci + off_b + 4);

        const float* f = filt + c * 9;           // uniform -> s_load path
        const float w00 = f[0] * m_top, w01 = f[1] * m_top, w02 = f[2] * m_top;
        const float w10 = f[3],         w11 = f[4],         w12 = f[5];
        const float w20 = f[6] * m_bot, w21 = f[7] * m_bot, w22 = f[8] * m_bot;

        row_conv(rt0, rt1, w00, w01, w02, lane, ar0, ar1);
        row_conv(rm0, rm1, w10, w11, w12, lane, ar0, ar1);
        row_conv(rb0, rb1, w20, w21, w22, lane, ar0, ar1);
        row_conv(it0, it1, w00, w01, w02, lane, ai0, ai1);
        row_conv(im0, im1, w10, w11, w12, lane, ai0, ai1);
        row_conv(ib0, ib1, w20, w21, w22, lane, ai0, ai1);
    }

    // ---- store (B, 2, NY, NX) ----
    float* o_re = out + ((size_t)(b * 2 + 0) * NY + y) * NX + x0;
    float* o_im = out + ((size_t)(b * 2 + 1) * NY + y) * NX + x0;
    *(float4*)(o_re)     = ar0;
    *(float4*)(o_re + 4) = ar1;
    *(float4*)(o_im)     = ai0;
    *(float4*)(o_im + 4) = ai1;
}

extern "C" void kernel_launch(void* const* d_in, const int* in_sizes, int n_in,
                              void* d_out, int out_size, void* d_ws, size_t ws_size,
                              hipStream_t stream) {
    const float* Rq_re    = (const float*)d_in[0];
    const float* Rq_im    = (const float*)d_in[1];
    const float* Dq_re    = (const float*)d_in[2];
    const float* Dq_im    = (const float*)d_in[3];
    const float* cache_re = (const float*)d_in[4];
    const float* cache_im = (const float*)d_in[5];
    const float* filt     = (const float*)d_in[6];
    float* out = (float*)d_out;

    dim3 block(256);
    dim3 grid(NY / 4, 8);   // 1024 blocks; in-kernel swizzle maps XCD->batch
    momentum_kernel<<<grid, block, 0, stream>>>(Rq_re, Rq_im, Dq_re, Dq_im,
                                                cache_re, cache_im, filt, out);
}

// Round 10
// 44.049 us; speedup vs baseline: 5.0433x; 1.1942x over previous
//
#include <hip/hip_runtime.h>

// B=8, C=12, Ny=Nx=512, 3x3 depthwise conv SAME pad=1, channel-reduced, + Rq + Dq.
// Round-10: plane-split TLP. One wave = one full 512-px row of ONE plane
// (re or im) -> 8192 waves (2x round 9). Keeps r9's winners: rolled channel
// loop, natural VGPR allocation (no launch_bounds cap), weight-masked y-halo,
// bijective XCD swizzle (batch k's y-range stays on XCD k).
// r4's plane-split failed from the 32-VGPR cap + locality-blind dispatch;
// both causes are removed here.
#define NY 512
#define NX 512
#define CC 12

__device__ __forceinline__ void row_conv(const float4& v0, const float4& v1,
                                         float w0, float w1, float w2, int lane,
                                         float4& a0, float4& a1)
{
    float l0 = __shfl_up(v1.w, 1);    // px 8i-1 from lane i-1
    if (lane == 0) l0 = 0.f;          // image left edge
    float r1 = __shfl_down(v0.x, 1);  // px 8i+8 from lane i+1
    if (lane == 63) r1 = 0.f;         // image right edge

    a0.x += w0*l0   + w1*v0.x + w2*v0.y;
    a0.y += w0*v0.x + w1*v0.y + w2*v0.z;
    a0.z += w0*v0.y + w1*v0.z + w2*v0.w;
    a0.w += w0*v0.z + w1*v0.w + w2*v1.x;
    a1.x += w0*v0.w + w1*v1.x + w2*v1.y;
    a1.y += w0*v1.x + w1*v1.y + w2*v1.z;
    a1.z += w0*v1.y + w1*v1.z + w2*v1.w;
    a1.w += w0*v1.z + w1*v1.w + w2*r1;
}

// Block: 256 threads = 4 waves: (y0,re),(y0,im),(y0+1,re),(y0+1,im).
// Grid (NY/2, B) = (256, 8) = 2048 blocks -> 8192 waves = all wave slots.
__global__ __launch_bounds__(256)
void momentum_kernel(const float* __restrict__ Rq_re, const float* __restrict__ Rq_im,
                     const float* __restrict__ Dq_re, const float* __restrict__ Dq_im,
                     const float* __restrict__ cache_re, const float* __restrict__ cache_im,
                     const float* __restrict__ filt, float* __restrict__ out)
{
    const int tid  = threadIdx.x;
    const int wave = tid >> 6;
    const int lane = tid & 63;

    // XCD swizzle: bid%8 = XCD k -> swz in [256k, 256(k+1)) -> batch k,
    // contiguous y pairs. 2048 % 8 == 0 -> bijective.
    const int bid = blockIdx.x + (int)(blockIdx.y * gridDim.x);
    const int swz = (bid & 7) * 256 + (bid >> 3);
    const int b   = swz >> 8;
    const int y   = (swz & 255) * 2 + (wave >> 1);
    const int p   = wave & 1;               // 0 = re, 1 = im

    const float* Rq    = p ? Rq_im    : Rq_re;
    const float* Dq    = p ? Dq_im    : Dq_re;
    const float* cache = p ? cache_im : cache_re;

    const int x0 = lane * 8;

    // y-halo: clamped row + 0/1 weight mask (wave-uniform, branch-free loads)
    const int   ym1   = (y > 0)      ? y - 1 : 0;
    const int   yp1   = (y < NY - 1) ? y + 1 : NY - 1;
    const float m_top = (y > 0)      ? 1.f : 0.f;
    const float m_bot = (y < NY - 1) ? 1.f : 0.f;

    const int off_t = ym1 * NX + x0;
    const int off_m = y   * NX + x0;
    const int off_b = yp1 * NX + x0;

    // ---- pointwise: Rq + Dq (4 independent loads, one batch) ----
    float4 a0, a1;
    {
        const int base = (b * NY + y) * NX + x0;
        const float4 q0 = *(const float4*)(Rq + base);
        const float4 q1 = *(const float4*)(Rq + base + 4);
        const float4 d0 = *(const float4*)(Dq + base);
        const float4 d1 = *(const float4*)(Dq + base + 4);
        a0 = make_float4(q0.x + d0.x, q0.y + d0.y, q0.z + d0.z, q0.w + d0.w);
        a1 = make_float4(q1.x + d1.x, q1.y + d1.y, q1.z + d1.z, q1.w + d1.w);
    }

    // ---- channel-reduced depthwise 3x3: 6 unconditional loads per channel ----
    const size_t PS = (size_t)NY * NX;
    const float* cbase = cache + (size_t)b * CC * PS;

    for (int c = 0; c < CC; ++c) {
        const float* pl = cbase + (size_t)c * PS;
        const float4 t0 = *(const float4*)(pl + off_t);
        const float4 t1 = *(const float4*)(pl + off_t + 4);
        const float4 m0 = *(const float4*)(pl + off_m);
        const float4 m1 = *(const float4*)(pl + off_m + 4);
        const float4 b0 = *(const float4*)(pl + off_b);
        const float4 b1 = *(const float4*)(pl + off_b + 4);

        const float* f = filt + c * 9;           // uniform -> s_load path
        const float w00 = f[0] * m_top, w01 = f[1] * m_top, w02 = f[2] * m_top;
        const float w10 = f[3],         w11 = f[4],         w12 = f[5];
        const float w20 = f[6] * m_bot, w21 = f[7] * m_bot, w22 = f[8] * m_bot;

        row_conv(t0, t1, w00, w01, w02, lane, a0, a1);
        row_conv(m0, m1, w10, w11, w12, lane, a0, a1);
        row_conv(b0, b1, w20, w21, w22, lane, a0, a1);
    }

    // ---- store (B, 2, NY, NX) ----
    float* o = out + ((size_t)(b * 2 + p) * NY + y) * NX + x0;
    *(float4*)(o)     = a0;
    *(float4*)(o + 4) = a1;
}

extern "C" void kernel_launch(void* const* d_in, const int* in_sizes, int n_in,
                              void* d_out, int out_size, void* d_ws, size_t ws_size,
                              hipStream_t stream) {
    const float* Rq_re    = (const float*)d_in[0];
    const float* Rq_im    = (const float*)d_in[1];
    const float* Dq_re    = (const float*)d_in[2];
    const float* Dq_im    = (const float*)d_in[3];
    const float* cache_re = (const float*)d_in[4];
    const float* cache_im = (const float*)d_in[5];
    const float* filt     = (const float*)d_in[6];
    float* out = (float*)d_out;

    dim3 block(256);
    dim3 grid(NY / 2, 8);   // 2048 blocks; in-kernel swizzle maps XCD->batch
    momentum_kernel<<<grid, block, 0, stream>>>(Rq_re, Rq_im, Dq_re, Dq_im,
                                                cache_re, cache_im, filt, out);
}